// Round 2
// baseline (496.208 us; speedup 1.0000x reference)
//
#include <hip/hip_runtime.h>
#include <hip/hip_bf16.h>

#define BB 4
#define TT 2048
#define CC 1024
#define HH 16
#define DD 64
#define MM (BB*TT)   // 8192 rows

typedef unsigned short u16;
typedef __bf16 bf16x8 __attribute__((ext_vector_type(8)));
typedef u16 u16x8 __attribute__((ext_vector_type(8)));
typedef u16 u16x4 __attribute__((ext_vector_type(4)));
typedef float f32x4 __attribute__((ext_vector_type(4)));

__device__ __forceinline__ u16 f2bf(float f) {
  union { float f; unsigned u; } v; v.f = f;
  unsigned u = v.u;
  return (u16)((u + 0x7fffu + ((u >> 16) & 1u)) >> 16);  // RNE
}
__device__ __forceinline__ float bf2f(u16 s) {
  union { unsigned u; float f; } v; v.u = ((unsigned)s) << 16; return v.f;
}
__device__ __forceinline__ bf16x8 ld_bf16x8(const u16* p) {
  return *reinterpret_cast<const bf16x8*>(p);
}
__device__ __forceinline__ bf16x8 as_bf16x8(u16x8 v) {
  union { u16x8 u; bf16x8 b; } c; c.u = v; return c.b;
}
__device__ __forceinline__ f32x4 zero4() {
  f32x4 z; z[0] = 0.f; z[1] = 0.f; z[2] = 0.f; z[3] = 0.f; return z;
}

// ---------------- cast x (fp32 -> bf16), vectorized ----------------
__global__ void k_cast_bf16(const float* __restrict__ x, u16* __restrict__ o, int n4) {
  int i = blockIdx.x * blockDim.x + threadIdx.x;
  if (i >= n4) return;
  const float4 v = reinterpret_cast<const float4*>(x)[i];
  u16x4 r; r.x = f2bf(v.x); r.y = f2bf(v.y); r.z = f2bf(v.z); r.w = f2bf(v.w);
  reinterpret_cast<u16x4*>(o)[i] = r;
}

// ---------------- transpose-cast W [K][N] fp32 -> Wt [N][K] bf16 ----------------
__global__ void k_transpose_bf16(const float* __restrict__ W, u16* __restrict__ Wt,
                                 int K, int N) {
  __shared__ float tile[32][33];
  int nb = blockIdx.x * 32, kb = blockIdx.y * 32;
  int tx = threadIdx.x & 31, ty = threadIdx.x >> 5;  // 256 thr: ty 0..7
  #pragma unroll
  for (int i = ty; i < 32; i += 8)
    tile[i][tx] = W[(size_t)(kb + i) * N + nb + tx];
  __syncthreads();
  #pragma unroll
  for (int i = ty; i < 32; i += 8)
    Wt[(size_t)(nb + i) * K + kb + tx] = f2bf(tile[tx][i]);
}

// ---------------- GEMM  C[M,N] = A[M,K](bf16) * Bt[N,K](bf16)^T ----------------
// 128x128 tile, BK=64, 4 waves in 2x2, each wave 4x4 of 16x16x32 MFMAs.
// LDS XOR swizzle: 16B chunk index ^ (row & 7) -> conflict-minimal staging + frag reads.
// EPI==0: fp32 row-major out.  EPI==1: scatter q->[B,H,T,D], k->[B,H,T,D], v->[B,H,D,T].
template<int EPI>
__global__ __launch_bounds__(256, 2)
void k_gemm_bt(const u16* __restrict__ A, const u16* __restrict__ Bt,
               float* __restrict__ outF, u16* __restrict__ qb, u16* __restrict__ kb,
               u16* __restrict__ vt, int N, int K)
{
  __shared__ u16 As[128 * 64];
  __shared__ u16 Bs[128 * 64];
  const int tid  = threadIdx.x;
  const int lane = tid & 63, w = tid >> 6;
  const int l16  = lane & 15, quad = lane >> 4;
  const int wr = w >> 1, wc = w & 1;
  const int m0 = blockIdx.y * 128, n0 = blockIdx.x * 128;
  const int col8 = tid & 7, row0 = tid >> 3;  // 8 thr/row, 32 rows/pass

  f32x4 acc[4][4];
  #pragma unroll
  for (int i = 0; i < 4; ++i)
    #pragma unroll
    for (int j = 0; j < 4; ++j) acc[i][j] = zero4();

  for (int k0 = 0; k0 < K; k0 += 64) {
    __syncthreads();
    #pragma unroll
    for (int r = row0; r < 128; r += 32) {
      u16x8 va = *reinterpret_cast<const u16x8*>(A  + (size_t)(m0 + r) * K + k0 + col8 * 8);
      *reinterpret_cast<u16x8*>(&As[r * 64 + (col8 ^ (r & 7)) * 8]) = va;
      u16x8 vb = *reinterpret_cast<const u16x8*>(Bt + (size_t)(n0 + r) * K + k0 + col8 * 8);
      *reinterpret_cast<u16x8*>(&Bs[r * 64 + (col8 ^ (r & 7)) * 8]) = vb;
    }
    __syncthreads();
    #pragma unroll
    for (int s = 0; s < 2; ++s) {
      bf16x8 af[4], bfr[4];
      #pragma unroll
      for (int i = 0; i < 4; ++i) {
        int mrow = wr * 64 + i * 16 + l16;
        af[i]  = ld_bf16x8(&As[mrow * 64 + ((s * 4 + quad) ^ (l16 & 7)) * 8]);
        int nrow = wc * 64 + i * 16 + l16;
        bfr[i] = ld_bf16x8(&Bs[nrow * 64 + ((s * 4 + quad) ^ (l16 & 7)) * 8]);
      }
      #pragma unroll
      for (int i = 0; i < 4; ++i)
        #pragma unroll
        for (int j = 0; j < 4; ++j)
          acc[i][j] = __builtin_amdgcn_mfma_f32_16x16x32_bf16(af[i], bfr[j], acc[i][j], 0, 0, 0);
    }
  }

  // epilogue: C/D layout col = lane&15, row = quad*4 + reg (m89-verified)
  #pragma unroll
  for (int i = 0; i < 4; ++i) {
    #pragma unroll
    for (int j = 0; j < 4; ++j) {
      #pragma unroll
      for (int r = 0; r < 4; ++r) {
        int m = m0 + wr * 64 + i * 16 + quad * 4 + r;
        int n = n0 + wc * 64 + j * 16 + l16;
        float v = acc[i][j][r];
        if (EPI == 0) {
          outF[(size_t)m * N + n] = v;
        } else {
          int b = m >> 11, t = m & 2047;  // T = 2048
          u16 bv = f2bf(v);
          if (n < CC) {
            int h = n >> 6, d = n & 63;
            qb[(((size_t)(b * HH + h) * TT + t) << 6) + d] = bv;
          } else if (n < 2 * CC) {
            int n2 = n - CC; int h = n2 >> 6, d = n2 & 63;
            kb[(((size_t)(b * HH + h) * TT + t) << 6) + d] = bv;
          } else {
            int n2 = n - 2 * CC; int h = n2 >> 6, d = n2 & 63;
            vt[((size_t)(b * HH + h) * DD + d) * TT + t] = bv;  // transposed [B,H,D,T]
          }
        }
      }
    }
  }
}

// ---------------- flash attention v2: barrierless, one wave per 16 q-rows ----------------
// K and V fragments loaded DIRECTLY from global into MFMA B-operand registers
// (16 B/lane dwordx4, wave-coalesced). No __syncthreads anywhere: waves are
// fully independent, so the compiler can hoist next-tile loads across softmax.
// P C-layout -> A-layout transform stays in wave-private LDS (lgkmcnt-ordered).
// Block = 4 waves on 4 consecutive q-chunks (work skew <= 1 tile); blocks
// ordered heavy-first (qg descending) to shrink the causal straggler tail.
__global__ __launch_bounds__(256, 4)
void k_attn(const u16* __restrict__ qb, const u16* __restrict__ kb,
            const u16* __restrict__ vt, u16* __restrict__ y)
{
  __shared__ u16 Ps[4 * 16 * 64];
  const int tid  = threadIdx.x;
  const int lane = tid & 63, w = tid >> 6;
  const int l16  = lane & 15, quad = lane >> 4;

  const int bx = blockIdx.x;
  const int bh = bx & 63;              // 64 (b,h) pairs
  const int qg = 31 - (bx >> 6);       // heavy q-groups first
  const int qc = qg * 4 + w;           // q-chunk 0..127 (16 rows each)
  const int h  = bh & 15, b = bh >> 4;

  const u16* qptr = qb + ((size_t)bh * TT + qc * 16) * DD;
  const u16* kptr = kb + (size_t)bh * TT * DD;
  const u16* vptr = vt + (size_t)bh * DD * TT;   // [D][T]

  // Q fragments (A-operand): lane l16 = m-row, quad*8 = k-chunk. Pre-scale by
  // 1/sqrt(D) = 0.125 (pow2 -> exact in bf16).
  bf16x8 qf[2];
  #pragma unroll
  for (int s = 0; s < 2; ++s) {
    u16x8 v = *reinterpret_cast<const u16x8*>(qptr + l16 * DD + s * 32 + quad * 8);
    u16x8 o;
    #pragma unroll
    for (int e = 0; e < 8; ++e) o[e] = f2bf(bf2f(v[e]) * 0.125f);
    qf[s] = as_bf16x8(o);
  }

  float mr[4], lr[4];
  f32x4 O[4];
  #pragma unroll
  for (int r = 0; r < 4; ++r) { mr[r] = -__builtin_inff(); lr[r] = 0.f; }
  #pragma unroll
  for (int j = 0; j < 4; ++j) O[j] = zero4();

  const int ktiles = (qc >> 2) + 1;
  for (int kt = 0; kt < ktiles; ++kt) {
    const u16* kt0 = kptr + (size_t)kt * 64 * DD;

    // K fragments (B-operand): row = j*16+l16, k-chunk = s*32+quad*8. All 8
    // loads issued before any MFMA -> deep VMEM pipeline, no barrier in sight.
    bf16x8 kf[4][2];
    #pragma unroll
    for (int j = 0; j < 4; ++j)
      #pragma unroll
      for (int s = 0; s < 2; ++s)
        kf[j][s] = ld_bf16x8(kt0 + (size_t)(j * 16 + l16) * DD + s * 32 + quad * 8);

    f32x4 S[4];
    #pragma unroll
    for (int j = 0; j < 4; ++j) S[j] = zero4();
    #pragma unroll
    for (int s = 0; s < 2; ++s)
      #pragma unroll
      for (int j = 0; j < 4; ++j)
        S[j] = __builtin_amdgcn_mfma_f32_16x16x32_bf16(qf[s], kf[j][s], S[j], 0, 0, 0);

    // V fragments (B-operand of PV): n = d = j*16+l16 (row of vt), k = t-offset.
    // Issued here so they overlap the softmax VALU below.
    bf16x8 vf[4][2];
    #pragma unroll
    for (int j = 0; j < 4; ++j)
      #pragma unroll
      for (int s = 0; s < 2; ++s)
        vf[j][s] = ld_bf16x8(vptr + (size_t)(j * 16 + l16) * TT + kt * 64 + s * 32 + quad * 8);

    if (kt == ktiles - 1) {  // only the last tile can cross the diagonal
      const int lq = (qc & 3) * 16 + quad * 4;  // local q row of reg r=0
      #pragma unroll
      for (int j = 0; j < 4; ++j)
        #pragma unroll
        for (int r = 0; r < 4; ++r)
          if (j * 16 + l16 > lq + r) S[j][r] = -__builtin_inff();
    }

    // online softmax: row stats reduced over the 16 lanes of each quad group
    float mt[4];
    #pragma unroll
    for (int r = 0; r < 4; ++r)
      mt[r] = fmaxf(fmaxf(S[0][r], S[1][r]), fmaxf(S[2][r], S[3][r]));
    #pragma unroll
    for (int off = 1; off <= 8; off <<= 1)
      #pragma unroll
      for (int r = 0; r < 4; ++r)
        mt[r] = fmaxf(mt[r], __shfl_xor(mt[r], off));
    float mnew[4], alpha[4], rs[4];
    #pragma unroll
    for (int r = 0; r < 4; ++r) {
      mnew[r]  = fmaxf(mr[r], mt[r]);
      alpha[r] = __expf(mr[r] - mnew[r]);   // exp(-inf)=0 on first tile
      rs[r] = 0.f;
    }
    #pragma unroll
    for (int j = 0; j < 4; ++j)
      #pragma unroll
      for (int r = 0; r < 4; ++r) {
        float p = __expf(S[j][r] - mnew[r]);
        S[j][r] = p;
        rs[r] += p;
      }
    #pragma unroll
    for (int off = 1; off <= 8; off <<= 1)
      #pragma unroll
      for (int r = 0; r < 4; ++r)
        rs[r] += __shfl_xor(rs[r], off);
    #pragma unroll
    for (int r = 0; r < 4; ++r) {
      lr[r] = lr[r] * alpha[r] + rs[r];
      mr[r] = mnew[r];
    }
    #pragma unroll
    for (int j = 0; j < 4; ++j)
      #pragma unroll
      for (int r = 0; r < 4; ++r)
        O[j][r] *= alpha[r];

    // P: C-layout -> wave-private LDS (bf16) -> A-layout. No barrier needed;
    // compiler orders the ds_write/ds_read pair via lgkmcnt.
    #pragma unroll
    for (int j = 0; j < 4; ++j)
      #pragma unroll
      for (int r = 0; r < 4; ++r) {
        int m = quad * 4 + r;
        int col = j * 16 + l16;
        Ps[w * 1024 + m * 64 + ((col >> 3) ^ (m & 7)) * 8 + (col & 7)] = f2bf(S[j][r]);
      }
    #pragma unroll
    for (int s = 0; s < 2; ++s) {
      bf16x8 pf = ld_bf16x8(&Ps[w * 1024 + l16 * 64 + ((s * 4 + quad) ^ (l16 & 7)) * 8]);
      #pragma unroll
      for (int j = 0; j < 4; ++j)
        O[j] = __builtin_amdgcn_mfma_f32_16x16x32_bf16(pf, vf[j][s], O[j], 0, 0, 0);
    }
  }

  // epilogue: O /= l, write y [B,T,C] bf16
  #pragma unroll
  for (int j = 0; j < 4; ++j)
    #pragma unroll
    for (int r = 0; r < 4; ++r) {
      int t  = qc * 16 + quad * 4 + r;
      int ch = h * 64 + j * 16 + l16;
      float val = O[j][r] / lr[r];
      y[(size_t)(b * TT + t) * CC + ch] = f2bf(val);
    }
}

extern "C" void kernel_launch(void* const* d_in, const int* in_sizes, int n_in,
                              void* d_out, int out_size, void* d_ws, size_t ws_size,
                              hipStream_t stream) {
  const float* x  = (const float*)d_in[0];   // [B,T,C]
  const float* Wa = (const float*)d_in[1];   // [C,3C]
  const float* Wp = (const float*)d_in[2];   // [C,C]
  float* out = (float*)d_out;                // [B,T,C] fp32

  // workspace layout (bf16/u16 elems), total ~92.3 MB
  u16* ws   = (u16*)d_ws;
  u16* xb   = ws;                             // M*C        = 8388608
  u16* Wab  = xb   + (size_t)MM * CC;         // 3C*C (W_attn^T) = 3145728
  u16* Wpb  = Wab  + (size_t)3 * CC * CC;     // C*C  (W_proj^T) = 1048576
  u16* qbuf = Wpb  + (size_t)CC * CC;         // [B,H,T,D]  = 8388608
  u16* kbuf = qbuf + (size_t)MM * CC;         // [B,H,T,D]
  u16* vtb  = kbuf + (size_t)MM * CC;         // [B,H,D,T]
  u16* yb   = vtb  + (size_t)MM * CC;         // [B,T,C]

  k_cast_bf16<<<(MM * CC / 4) / 256, 256, 0, stream>>>(x, xb, MM * CC / 4);
  k_transpose_bf16<<<dim3(3 * CC / 32, CC / 32), 256, 0, stream>>>(Wa, Wab, CC, 3 * CC);
  k_transpose_bf16<<<dim3(CC / 32, CC / 32), 256, 0, stream>>>(Wp, Wpb, CC, CC);
  k_gemm_bt<1><<<dim3(3 * CC / 128, MM / 128), 256, 0, stream>>>(
      xb, Wab, nullptr, qbuf, kbuf, vtb, 3 * CC, CC);
  k_attn<<<64 * 32, 256, 0, stream>>>(qbuf, kbuf, vtb, yb);
  k_gemm_bt<0><<<dim3(CC / 128, MM / 128), 256, 0, stream>>>(
      yb, Wpb, out, nullptr, nullptr, nullptr, CC, CC);
}

// Round 4
// 316.334 us; speedup vs baseline: 1.5686x; 1.5686x over previous
//
#include <hip/hip_runtime.h>
#include <hip/hip_bf16.h>

#define BB 4
#define TT 2048
#define CC 1024
#define HH 16
#define DD 64
#define MM (BB*TT)   // 8192 rows

typedef unsigned short u16;
typedef __bf16 bf16x8 __attribute__((ext_vector_type(8)));
typedef u16 u16x8 __attribute__((ext_vector_type(8)));
typedef u16 u16x4 __attribute__((ext_vector_type(4)));
typedef float f32x4 __attribute__((ext_vector_type(4)));

__device__ __forceinline__ u16 f2bf(float f) {
  union { float f; unsigned u; } v; v.f = f;
  unsigned u = v.u;
  return (u16)((u + 0x7fffu + ((u >> 16) & 1u)) >> 16);  // RNE
}
__device__ __forceinline__ float bf2f(u16 s) {
  union { unsigned u; float f; } v; v.u = ((unsigned)s) << 16; return v.f;
}
__device__ __forceinline__ bf16x8 ld_bf16x8(const u16* p) {
  return *reinterpret_cast<const bf16x8*>(p);
}
__device__ __forceinline__ f32x4 zero4() {
  f32x4 z; z[0] = 0.f; z[1] = 0.f; z[2] = 0.f; z[3] = 0.f; return z;
}

// async global->LDS DMA, 16 B/lane. LDS dest = wave-uniform base + lane*16.
__device__ __forceinline__ void gld_lds16(const u16* g, u16* l) {
  __builtin_amdgcn_global_load_lds(
      (const __attribute__((address_space(1))) void*)g,
      (__attribute__((address_space(3))) void*)l, 16, 0, 0);
}
// explicit drain of LDS-DMA: s_waitcnt vmcnt(0) (exp=7, lgkm=15 -> no-op there)
__device__ __forceinline__ void wait_vm0() { __builtin_amdgcn_s_waitcnt(0x0F70); }

// DPP row_ror reductions (row = 16 lanes, aligns with our quad groups). Pure
// VALU — keeps softmax off the LDS pipe (shfl_xor compiles to ds_swizzle).
template <int CTRL>
__device__ __forceinline__ float dpp_mov(float x) {
  int xi = __builtin_bit_cast(int, x);
  int r = __builtin_amdgcn_update_dpp(xi, xi, CTRL, 0xF, 0xF, false);
  return __builtin_bit_cast(float, r);
}
__device__ __forceinline__ float row16_max(float x) {
  x = fmaxf(x, dpp_mov<0x128>(x));  // row_ror:8
  x = fmaxf(x, dpp_mov<0x124>(x));  // row_ror:4
  x = fmaxf(x, dpp_mov<0x122>(x));  // row_ror:2
  x = fmaxf(x, dpp_mov<0x121>(x));  // row_ror:1
  return x;
}
__device__ __forceinline__ float row16_sum(float x) {
  x += dpp_mov<0x128>(x);
  x += dpp_mov<0x124>(x);
  x += dpp_mov<0x122>(x);
  x += dpp_mov<0x121>(x);
  return x;
}

// ---------------- cast x (fp32 -> bf16), vectorized ----------------
__global__ void k_cast_bf16(const float* __restrict__ x, u16* __restrict__ o, int n4) {
  int i = blockIdx.x * blockDim.x + threadIdx.x;
  if (i >= n4) return;
  const float4 v = reinterpret_cast<const float4*>(x)[i];
  u16x4 r; r.x = f2bf(v.x); r.y = f2bf(v.y); r.z = f2bf(v.z); r.w = f2bf(v.w);
  reinterpret_cast<u16x4*>(o)[i] = r;
}

// ---------------- transpose-cast W [K][N] fp32 -> Wt [N][K] bf16 ----------------
__global__ void k_transpose_bf16(const float* __restrict__ W, u16* __restrict__ Wt,
                                 int K, int N) {
  __shared__ float tile[32][33];
  int nb = blockIdx.x * 32, kb = blockIdx.y * 32;
  int tx = threadIdx.x & 31, ty = threadIdx.x >> 5;
  #pragma unroll
  for (int i = ty; i < 32; i += 8)
    tile[i][tx] = W[(size_t)(kb + i) * N + nb + tx];
  __syncthreads();
  #pragma unroll
  for (int i = ty; i < 32; i += 8)
    Wt[(size_t)(nb + i) * K + kb + tx] = f2bf(tile[tx][i]);
}

// ---------------- GEMM  C[M,N] = A[M,K](bf16) * Bt[N,K](bf16)^T ----------------
// m97-proven shape: stage(DMA) -> drain -> barrier -> compute -> barrier.
// XOR swizzle on the GLOBAL address side (per-lane gather) so the lane-ordered
// LDS DMA lands swizzled; frag reads conflict-free (r1 measured: 0 conflicts).
template<int EPI>
__global__ __launch_bounds__(256, 2)
void k_gemm_bt(const u16* __restrict__ A, const u16* __restrict__ Bt,
               float* __restrict__ outF, u16* __restrict__ qb, u16* __restrict__ kb,
               u16* __restrict__ vt, int N, int K)
{
  __shared__ u16 As[128 * 64];
  __shared__ u16 Bs[128 * 64];
  const int tid  = threadIdx.x;
  const int lane = tid & 63, w = tid >> 6;
  const int l16  = lane & 15, quad = lane >> 4;
  const int wr = w >> 1, wc = w & 1;
  const int m0 = blockIdx.y * 128, n0 = blockIdx.x * 128;
  const int lr8 = lane >> 3, lc8 = lane & 7;

  f32x4 acc[4][4];
  #pragma unroll
  for (int i = 0; i < 4; ++i)
    #pragma unroll
    for (int j = 0; j < 4; ++j) acc[i][j] = zero4();

  for (int k0 = 0; k0 < K; k0 += 64) {
    __syncthreads();
    // wave w stages rows [w*32, w*32+32): 8 DMA insts, zero staging VGPRs
    #pragma unroll
    for (int p = 0; p < 4; ++p) {
      const int row = w * 32 + p * 8 + lr8;
      const int cs  = lc8 ^ (row & 7);
      gld_lds16(A  + (size_t)(m0 + row) * K + k0 + cs * 8, &As[(w * 32 + p * 8) * 64]);
      gld_lds16(Bt + (size_t)(n0 + row) * K + k0 + cs * 8, &Bs[(w * 32 + p * 8) * 64]);
    }
    wait_vm0();          // explicit LDS-DMA drain (belt & suspenders)
    __syncthreads();
    #pragma unroll
    for (int s = 0; s < 2; ++s) {
      bf16x8 af[4], bfr[4];
      #pragma unroll
      for (int i = 0; i < 4; ++i) {
        int mrow = wr * 64 + i * 16 + l16;
        af[i]  = ld_bf16x8(&As[mrow * 64 + ((s * 4 + quad) ^ (l16 & 7)) * 8]);
        int nrow = wc * 64 + i * 16 + l16;
        bfr[i] = ld_bf16x8(&Bs[nrow * 64 + ((s * 4 + quad) ^ (l16 & 7)) * 8]);
      }
      #pragma unroll
      for (int i = 0; i < 4; ++i)
        #pragma unroll
        for (int j = 0; j < 4; ++j)
          acc[i][j] = __builtin_amdgcn_mfma_f32_16x16x32_bf16(af[i], bfr[j], acc[i][j], 0, 0, 0);
    }
  }

  // epilogue: C/D layout col = lane&15, row = quad*4 + reg (m89-verified)
  #pragma unroll
  for (int i = 0; i < 4; ++i) {
    #pragma unroll
    for (int j = 0; j < 4; ++j) {
      #pragma unroll
      for (int r = 0; r < 4; ++r) {
        int m = m0 + wr * 64 + i * 16 + quad * 4 + r;
        int n = n0 + wc * 64 + j * 16 + l16;
        float v = acc[i][j][r];
        if (EPI == 0) {
          outF[(size_t)m * N + n] = v;
        } else {
          int b = m >> 11, t = m & 2047;  // T = 2048
          u16 bv = f2bf(v);
          if (n < CC) {
            int h = n >> 6, d = n & 63;
            qb[(((size_t)(b * HH + h) * TT + t) << 6) + d] = bv;
          } else if (n < 2 * CC) {
            int n2 = n - CC; int h = n2 >> 6, d = n2 & 63;
            kb[(((size_t)(b * HH + h) * TT + t) << 6) + d] = bv;
          } else {
            int n2 = n - 2 * CC; int h = n2 >> 6, d = n2 & 63;
            vt[((size_t)(b * HH + h) * DD + d) * TT + t] = bv;  // transposed [B,H,D,T]
          }
        }
      }
    }
  }
}

// ---------------- flash attention v4: two-barrier proven shape ----------------
// Per K-tile: stage(DMA K,V) -> vmcnt(0) -> barrier -> compute -> barrier.
// No cross-iteration DMA (r3's race suspect). Keeps: DPP softmax, exp2 domain,
// heavy-q-first, single 24 KB LDS footprint -> 4 blocks/CU (16 waves/CU) so
// inter-wave overlap hides the barrier drain (m114).
__global__ __launch_bounds__(256, 4)
void k_attn(const u16* __restrict__ qb, const u16* __restrict__ kb,
            const u16* __restrict__ vt, u16* __restrict__ y)
{
  __shared__ u16 Ks[64 * 64];
  __shared__ u16 Vs[64 * 64];
  __shared__ u16 QP[64 * 64];   // Q staging (prologue) then P transform (loop)
  const int tid  = threadIdx.x;
  const int lane = tid & 63, w = tid >> 6;
  const int l16  = lane & 15, quad = lane >> 4;
  const int lr8 = lane >> 3, lc8 = lane & 7;

  const int bx = blockIdx.x;
  const int qt = 31 - (bx >> 6);       // heavy q-tiles first
  const int bh = bx & 63;
  const int h  = bh & 15, b = bh >> 4;

  const u16* qptr = qb + ((size_t)bh * TT + qt * 64) * DD;
  const u16* kptr = kb + (size_t)bh * TT * DD;
  const u16* vptr = vt + (size_t)bh * DD * TT;   // [D][T]

  // Q: wave-private staging (rows w*16..+16) + frag read; prescale by
  // 1/sqrt(D)*log2(e) so softmax runs in exp2 domain.
  const float qscale = 0.125f * 1.44269504088896340736f;
  #pragma unroll
  for (int p = 0; p < 2; ++p) {
    const int r = w * 16 + p * 8 + lr8;
    u16x8 v = *reinterpret_cast<const u16x8*>(qptr + (size_t)r * DD + lc8 * 8);
    u16x8 o;
    #pragma unroll
    for (int e = 0; e < 8; ++e) o[e] = f2bf(bf2f(v[e]) * qscale);
    *reinterpret_cast<u16x8*>(&QP[r * 64 + (lc8 ^ lr8) * 8]) = o;
  }
  bf16x8 qf[2];
  #pragma unroll
  for (int s = 0; s < 2; ++s)
    qf[s] = ld_bf16x8(&QP[(w * 16 + l16) * 64 + ((s * 4 + quad) ^ (l16 & 7)) * 8]);

  float mr[4], lr[4];
  f32x4 O[4];
  #pragma unroll
  for (int r = 0; r < 4; ++r) { mr[r] = -__builtin_inff(); lr[r] = 0.f; }
  #pragma unroll
  for (int j = 0; j < 4; ++j) O[j] = zero4();

  const int ktiles = qt + 1;
  for (int kt = 0; kt < ktiles; ++kt) {
    __syncthreads();   // all prior-tile frag reads complete before restaging
    {
      const u16* kt0 = kptr + (size_t)kt * 64 * DD;
      const u16* vt0 = vptr + kt * 64;
      #pragma unroll
      for (int p = 0; p < 2; ++p) {
        const int row = w * 16 + p * 8 + lr8;
        const int cs  = lc8 ^ lr8;
        gld_lds16(kt0 + (size_t)row * DD + cs * 8, &Ks[(w * 16 + p * 8) * 64]);
        gld_lds16(vt0 + (size_t)row * TT + cs * 8, &Vs[(w * 16 + p * 8) * 64]);
      }
    }
    wait_vm0();          // own DMA landed
    __syncthreads();     // everyone's DMA landed

    // S = Q K^T (log2 domain)
    f32x4 S[4];
    #pragma unroll
    for (int j = 0; j < 4; ++j) S[j] = zero4();
    #pragma unroll
    for (int s = 0; s < 2; ++s) {
      #pragma unroll
      for (int j = 0; j < 4; ++j) {
        bf16x8 kf = ld_bf16x8(&Ks[(j * 16 + l16) * 64 + ((s * 4 + quad) ^ (l16 & 7)) * 8]);
        S[j] = __builtin_amdgcn_mfma_f32_16x16x32_bf16(qf[s], kf, S[j], 0, 0, 0);
      }
    }
    if (kt == qt) {  // diagonal tile: causal mask (local indices)
      #pragma unroll
      for (int j = 0; j < 4; ++j)
        #pragma unroll
        for (int r = 0; r < 4; ++r) {
          int kg = j * 16 + l16;
          int qg = w * 16 + quad * 4 + r;
          if (kg > qg) S[j][r] = -__builtin_inff();
        }
    }

    // online softmax (exp2 domain), DPP reductions over 16-lane row groups
    float mt[4];
    #pragma unroll
    for (int r = 0; r < 4; ++r)
      mt[r] = row16_max(fmaxf(fmaxf(S[0][r], S[1][r]), fmaxf(S[2][r], S[3][r])));
    float mnew[4], alpha[4], rs[4];
    #pragma unroll
    for (int r = 0; r < 4; ++r) {
      mnew[r]  = fmaxf(mr[r], mt[r]);
      alpha[r] = exp2f(mr[r] - mnew[r]);   // exp2(-inf)=0 on first tile
      rs[r] = 0.f;
    }
    #pragma unroll
    for (int j = 0; j < 4; ++j)
      #pragma unroll
      for (int r = 0; r < 4; ++r) {
        float p = exp2f(S[j][r] - mnew[r]);
        S[j][r] = p;
        rs[r] += p;
      }
    #pragma unroll
    for (int r = 0; r < 4; ++r) {
      rs[r] = row16_sum(rs[r]);
      lr[r] = lr[r] * alpha[r] + rs[r];
      mr[r] = mnew[r];
    }
    #pragma unroll
    for (int j = 0; j < 4; ++j)
      #pragma unroll
      for (int r = 0; r < 4; ++r)
        O[j][r] *= alpha[r];

    // P: C-layout -> wave-private LDS region -> A-layout (lgkmcnt-ordered)
    #pragma unroll
    for (int j = 0; j < 4; ++j)
      #pragma unroll
      for (int r = 0; r < 4; ++r) {
        int m = quad * 4 + r;
        int col = j * 16 + l16;
        QP[w * 1024 + m * 64 + ((col >> 3) ^ (m & 7)) * 8 + (col & 7)] = f2bf(S[j][r]);
      }
    #pragma unroll
    for (int s = 0; s < 2; ++s) {
      bf16x8 pf = ld_bf16x8(&QP[w * 1024 + l16 * 64 + ((s * 4 + quad) ^ (l16 & 7)) * 8]);
      #pragma unroll
      for (int j = 0; j < 4; ++j) {
        bf16x8 vf = ld_bf16x8(&Vs[(j * 16 + l16) * 64 + ((s * 4 + quad) ^ (l16 & 7)) * 8]);
        O[j] = __builtin_amdgcn_mfma_f32_16x16x32_bf16(pf, vf, O[j], 0, 0, 0);
      }
    }
  }

  // epilogue: O /= l, write y [B,T,C] bf16
  #pragma unroll
  for (int j = 0; j < 4; ++j)
    #pragma unroll
    for (int r = 0; r < 4; ++r) {
      int t  = qt * 64 + w * 16 + quad * 4 + r;
      int ch = h * 64 + j * 16 + l16;
      float val = O[j][r] / lr[r];
      y[(size_t)(b * TT + t) * CC + ch] = f2bf(val);
    }
}

extern "C" void kernel_launch(void* const* d_in, const int* in_sizes, int n_in,
                              void* d_out, int out_size, void* d_ws, size_t ws_size,
                              hipStream_t stream) {
  const float* x  = (const float*)d_in[0];   // [B,T,C]
  const float* Wa = (const float*)d_in[1];   // [C,3C]
  const float* Wp = (const float*)d_in[2];   // [C,C]
  float* out = (float*)d_out;                // [B,T,C] fp32

  u16* ws   = (u16*)d_ws;
  u16* xb   = ws;                             // M*C
  u16* Wab  = xb   + (size_t)MM * CC;         // 3C*C (W_attn^T)
  u16* Wpb  = Wab  + (size_t)3 * CC * CC;     // C*C  (W_proj^T)
  u16* qbuf = Wpb  + (size_t)CC * CC;         // [B,H,T,D]
  u16* kbuf = qbuf + (size_t)MM * CC;         // [B,H,T,D]
  u16* vtb  = kbuf + (size_t)MM * CC;         // [B,H,D,T]
  u16* yb   = vtb  + (size_t)MM * CC;         // [B,T,C]

  k_cast_bf16<<<(MM * CC / 4) / 256, 256, 0, stream>>>(x, xb, MM * CC / 4);
  k_transpose_bf16<<<dim3(3 * CC / 32, CC / 32), 256, 0, stream>>>(Wa, Wab, CC, 3 * CC);
  k_transpose_bf16<<<dim3(CC / 32, CC / 32), 256, 0, stream>>>(Wp, Wpb, CC, CC);
  k_gemm_bt<1><<<dim3(3 * CC / 128, MM / 128), 256, 0, stream>>>(
      xb, Wab, nullptr, qbuf, kbuf, vtb, 3 * CC, CC);
  k_attn<<<64 * 32, 256, 0, stream>>>(qbuf, kbuf, vtb, yb);
  k_gemm_bt<0><<<dim3(CC / 128, MM / 128), 256, 0, stream>>>(
      yb, Wpb, out, nullptr, nullptr, nullptr, CC, CC);
}

// Round 5
// 271.225 us; speedup vs baseline: 1.8295x; 1.1663x over previous
//
#include <hip/hip_runtime.h>
#include <hip/hip_bf16.h>

#define BB 4
#define TT 2048
#define CC 1024
#define HH 16
#define DD 64
#define MM (BB*TT)   // 8192 rows

typedef unsigned short u16;
typedef __bf16 bf16x8 __attribute__((ext_vector_type(8)));
typedef __bf16 bf16x4v __attribute__((ext_vector_type(4)));
typedef u16 u16x8 __attribute__((ext_vector_type(8)));
typedef u16 u16x4 __attribute__((ext_vector_type(4)));
typedef float f32x4 __attribute__((ext_vector_type(4)));

__device__ __forceinline__ u16 f2bf(float f) {
  union { float f; unsigned u; } v; v.f = f;
  unsigned u = v.u;
  return (u16)((u + 0x7fffu + ((u >> 16) & 1u)) >> 16);  // RNE
}
__device__ __forceinline__ float bf2f(u16 s) {
  union { unsigned u; float f; } v; v.u = ((unsigned)s) << 16; return v.f;
}
__device__ __forceinline__ bf16x8 ld_bf16x8(const u16* p) {
  return *reinterpret_cast<const bf16x8*>(p);
}
__device__ __forceinline__ f32x4 zero4() {
  f32x4 z; z[0] = 0.f; z[1] = 0.f; z[2] = 0.f; z[3] = 0.f; return z;
}

// async global->LDS DMA, 16 B/lane. LDS dest = wave-uniform base + lane*16.
__device__ __forceinline__ void gld_lds16(const u16* g, u16* l) {
  __builtin_amdgcn_global_load_lds(
      (const __attribute__((address_space(1))) void*)g,
      (__attribute__((address_space(3))) void*)l, 16, 0, 0);
}
// explicit drain of LDS-DMA: s_waitcnt vmcnt(0)
__device__ __forceinline__ void wait_vm0() { __builtin_amdgcn_s_waitcnt(0x0F70); }

// pull value from lane `srclane` (0..63) of the wave
__device__ __forceinline__ float lane_pull(float x, int srclane) {
  int r = __builtin_amdgcn_ds_bpermute(srclane << 2, __builtin_bit_cast(int, x));
  return __builtin_bit_cast(float, r);
}

// ---------------- cast x (fp32 -> bf16), vectorized ----------------
__global__ void k_cast_bf16(const float* __restrict__ x, u16* __restrict__ o, int n4) {
  int i = blockIdx.x * blockDim.x + threadIdx.x;
  if (i >= n4) return;
  const float4 v = reinterpret_cast<const float4*>(x)[i];
  u16x4 r; r.x = f2bf(v.x); r.y = f2bf(v.y); r.z = f2bf(v.z); r.w = f2bf(v.w);
  reinterpret_cast<u16x4*>(o)[i] = r;
}

// ---------------- transpose-cast W [K][N] fp32 -> Wt [N][K] bf16 ----------------
__global__ void k_transpose_bf16(const float* __restrict__ W, u16* __restrict__ Wt,
                                 int K, int N) {
  __shared__ float tile[32][33];
  int nb = blockIdx.x * 32, kb = blockIdx.y * 32;
  int tx = threadIdx.x & 31, ty = threadIdx.x >> 5;
  #pragma unroll
  for (int i = ty; i < 32; i += 8)
    tile[i][tx] = W[(size_t)(kb + i) * N + nb + tx];
  __syncthreads();
  #pragma unroll
  for (int i = ty; i < 32; i += 8)
    Wt[(size_t)(nb + i) * K + kb + tx] = f2bf(tile[tx][i]);
}

// ---------------- GEMM  C[M,N] = A[M,K](bf16) * Bt[N,K](bf16)^T ----------------
// m97-proven shape: stage(DMA) -> drain -> barrier -> compute -> barrier.
template<int EPI>
__global__ __launch_bounds__(256, 2)
void k_gemm_bt(const u16* __restrict__ A, const u16* __restrict__ Bt,
               float* __restrict__ outF, u16* __restrict__ qb, u16* __restrict__ kb,
               u16* __restrict__ vt, int N, int K)
{
  __shared__ u16 As[128 * 64];
  __shared__ u16 Bs[128 * 64];
  const int tid  = threadIdx.x;
  const int lane = tid & 63, w = tid >> 6;
  const int l16  = lane & 15, quad = lane >> 4;
  const int wr = w >> 1, wc = w & 1;
  const int m0 = blockIdx.y * 128, n0 = blockIdx.x * 128;
  const int lr8 = lane >> 3, lc8 = lane & 7;

  f32x4 acc[4][4];
  #pragma unroll
  for (int i = 0; i < 4; ++i)
    #pragma unroll
    for (int j = 0; j < 4; ++j) acc[i][j] = zero4();

  for (int k0 = 0; k0 < K; k0 += 64) {
    __syncthreads();
    #pragma unroll
    for (int p = 0; p < 4; ++p) {
      const int row = w * 32 + p * 8 + lr8;
      const int cs  = lc8 ^ (row & 7);
      gld_lds16(A  + (size_t)(m0 + row) * K + k0 + cs * 8, &As[(w * 32 + p * 8) * 64]);
      gld_lds16(Bt + (size_t)(n0 + row) * K + k0 + cs * 8, &Bs[(w * 32 + p * 8) * 64]);
    }
    wait_vm0();
    __syncthreads();
    #pragma unroll
    for (int s = 0; s < 2; ++s) {
      bf16x8 af[4], bfr[4];
      #pragma unroll
      for (int i = 0; i < 4; ++i) {
        int mrow = wr * 64 + i * 16 + l16;
        af[i]  = ld_bf16x8(&As[mrow * 64 + ((s * 4 + quad) ^ (l16 & 7)) * 8]);
        int nrow = wc * 64 + i * 16 + l16;
        bfr[i] = ld_bf16x8(&Bs[nrow * 64 + ((s * 4 + quad) ^ (l16 & 7)) * 8]);
      }
      #pragma unroll
      for (int i = 0; i < 4; ++i)
        #pragma unroll
        for (int j = 0; j < 4; ++j)
          acc[i][j] = __builtin_amdgcn_mfma_f32_16x16x32_bf16(af[i], bfr[j], acc[i][j], 0, 0, 0);
    }
  }

  // epilogue: C/D layout col = lane&15, row = quad*4 + reg (m89-verified)
  #pragma unroll
  for (int i = 0; i < 4; ++i) {
    #pragma unroll
    for (int j = 0; j < 4; ++j) {
      #pragma unroll
      for (int r = 0; r < 4; ++r) {
        int m = m0 + wr * 64 + i * 16 + quad * 4 + r;
        int n = n0 + wc * 64 + j * 16 + l16;
        float v = acc[i][j][r];
        if (EPI == 0) {
          outF[(size_t)m * N + n] = v;
        } else {
          int b = m >> 11, t = m & 2047;  // T = 2048
          u16 bv = f2bf(v);
          if (n < CC) {
            int h = n >> 6, d = n & 63;
            qb[(((size_t)(b * HH + h) * TT + t) << 6) + d] = bv;
          } else if (n < 2 * CC) {
            int n2 = n - CC; int h = n2 >> 6, d = n2 & 63;
            kb[(((size_t)(b * HH + h) * TT + t) << 6) + d] = bv;
          } else {
            int n2 = n - 2 * CC; int h = n2 >> 6, d = n2 & 63;
            vt[((size_t)(b * HH + h) * DD + d) * TT + t] = bv;  // transposed [B,H,D,T]
          }
        }
      }
    }
  }
}

// ---------------- flash attention v5: S^T layout ----------------
// S^T = mfma(A=K-frag, B=Q-frag): for 16x16x32, A and B operand layouts are
// identical, so fragments are unchanged — only operand order swaps. C-layout
// of S^T puts col = l16 = q-row: ALL 16 scores in a lane belong to ONE q-row.
//  -> softmax stats are scalars/lane (was x4), cross-lane reduce = 2 shfl_xor
//  -> P repack: 4 k-contiguous values/j -> cvt_pk casts + 4x ds_write_b64
//  -> alpha / 1/l redistributed to O layout (row=quad*4+r) via 4 ds_bpermute
// Two-barrier DMA staging shape retained (r4-proven, race-free).
__global__ __launch_bounds__(256, 6)
void k_attn(const u16* __restrict__ qb, const u16* __restrict__ kb,
            const u16* __restrict__ vt, u16* __restrict__ y)
{
  __shared__ u16 Ks[64 * 64];
  __shared__ u16 Vs[64 * 64];
  __shared__ u16 QP[64 * 64];   // Q staging (prologue) then P transform (loop)
  const int tid  = threadIdx.x;
  const int lane = tid & 63, w = tid >> 6;
  const int l16  = lane & 15, quad = lane >> 4;
  const int lr8 = lane >> 3, lc8 = lane & 7;

  const int bx = blockIdx.x;
  const int qt = 31 - (bx >> 6);       // heavy q-tiles first
  const int bh = bx & 63;
  const int h  = bh & 15, b = bh >> 4;

  const u16* qptr = qb + ((size_t)bh * TT + qt * 64) * DD;
  const u16* kptr = kb + (size_t)bh * TT * DD;
  const u16* vptr = vt + (size_t)bh * DD * TT;   // [D][T]

  // Q: wave-private staging (rows w*16..+16) + frag read; prescale by
  // 1/sqrt(D)*log2(e) -> softmax in exp2 domain.
  const float qscale = 0.125f * 1.44269504088896340736f;
  #pragma unroll
  for (int p = 0; p < 2; ++p) {
    const int r = w * 16 + p * 8 + lr8;
    u16x8 v = *reinterpret_cast<const u16x8*>(qptr + (size_t)r * DD + lc8 * 8);
    u16x8 o;
    #pragma unroll
    for (int e = 0; e < 8; ++e) o[e] = f2bf(bf2f(v[e]) * qscale);
    *reinterpret_cast<u16x8*>(&QP[r * 64 + (lc8 ^ lr8) * 8]) = o;
  }
  bf16x8 qf[2];
  #pragma unroll
  for (int s = 0; s < 2; ++s)
    qf[s] = ld_bf16x8(&QP[(w * 16 + l16) * 64 + ((s * 4 + quad) ^ (l16 & 7)) * 8]);

  float mrow = -__builtin_inff(), lrow = 0.f;   // stats for q-row w*16+l16
  f32x4 O[4];
  #pragma unroll
  for (int j = 0; j < 4; ++j) O[j] = zero4();

  const int ktiles = qt + 1;
  for (int kt = 0; kt < ktiles; ++kt) {
    __syncthreads();   // all prior-tile frag reads complete before restaging
    {
      const u16* kt0 = kptr + (size_t)kt * 64 * DD;
      const u16* vt0 = vptr + kt * 64;
      #pragma unroll
      for (int p = 0; p < 2; ++p) {
        const int row = w * 16 + p * 8 + lr8;
        const int cs  = lc8 ^ lr8;
        gld_lds16(kt0 + (size_t)row * DD + cs * 8, &Ks[(w * 16 + p * 8) * 64]);
        gld_lds16(vt0 + (size_t)row * TT + cs * 8, &Vs[(w * 16 + p * 8) * 64]);
      }
    }
    wait_vm0();          // own DMA landed
    __syncthreads();     // everyone's DMA landed

    // S^T[k = j*16+quad*4+r][q = l16] : A = K-frag, B = Q-frag (same layouts)
    f32x4 St[4];
    #pragma unroll
    for (int j = 0; j < 4; ++j) St[j] = zero4();
    #pragma unroll
    for (int s = 0; s < 2; ++s) {
      #pragma unroll
      for (int j = 0; j < 4; ++j) {
        bf16x8 kfr = ld_bf16x8(&Ks[(j * 16 + l16) * 64 + ((s * 4 + quad) ^ (l16 & 7)) * 8]);
        St[j] = __builtin_amdgcn_mfma_f32_16x16x32_bf16(kfr, qf[s], St[j], 0, 0, 0);
      }
    }
    if (kt == qt) {  // diagonal tile: causal mask (local: k > q -> -inf)
      const int qg = w * 16 + l16;
      #pragma unroll
      for (int j = 0; j < 4; ++j)
        #pragma unroll
        for (int r = 0; r < 4; ++r)
          if (j * 16 + quad * 4 + r > qg) St[j][r] = -__builtin_inff();
    }

    // online softmax (exp2 domain); per-lane scalar stats for q = w*16+l16
    float mloc = St[0][0];
    #pragma unroll
    for (int j = 0; j < 4; ++j)
      #pragma unroll
      for (int r = 0; r < 4; ++r) mloc = fmaxf(mloc, St[j][r]);
    mloc = fmaxf(mloc, __shfl_xor(mloc, 16));
    mloc = fmaxf(mloc, __shfl_xor(mloc, 32));
    const float mnew  = fmaxf(mrow, mloc);
    const float alpha = exp2f(mrow - mnew);   // exp2(-inf)=0 on first tile
    float rsum = 0.f;
    #pragma unroll
    for (int j = 0; j < 4; ++j)
      #pragma unroll
      for (int r = 0; r < 4; ++r) {
        float p = exp2f(St[j][r] - mnew);
        St[j][r] = p;
        rsum += p;
      }
    rsum += __shfl_xor(rsum, 16);
    rsum += __shfl_xor(rsum, 32);
    lrow = lrow * alpha + rsum;
    mrow = mnew;

    // alpha -> O layout (row = quad*4+r): pull from lane quad*4+r (l16 == q)
    f32x4 av;
    #pragma unroll
    for (int r = 0; r < 4; ++r) av[r] = lane_pull(alpha, quad * 4 + r);
    #pragma unroll
    for (int j = 0; j < 4; ++j) O[j] *= av;

    // P repack: lane holds k = j*16+quad*4+{0..3} of q-row l16 (k-contiguous!)
    // -> 2x v_cvt_pk + one ds_write_b64 per j, into the swizzled A-read layout.
    #pragma unroll
    for (int j = 0; j < 4; ++j) {
      union { bf16x4v b; u16x4 u; } cv;
      cv.b[0] = (__bf16)St[j][0]; cv.b[1] = (__bf16)St[j][1];
      cv.b[2] = (__bf16)St[j][2]; cv.b[3] = (__bf16)St[j][3];
      const int c = j * 2 + (quad >> 1);               // 16B chunk of k-granule
      const int off = w * 1024 + l16 * 64 + ((c ^ (l16 & 7)) << 3) + ((quad & 1) << 2);
      *reinterpret_cast<u16x4*>(&QP[off]) = cv.u;
    }
    #pragma unroll
    for (int s = 0; s < 2; ++s) {
      bf16x8 pf = ld_bf16x8(&QP[w * 1024 + l16 * 64 + ((s * 4 + quad) ^ (l16 & 7)) * 8]);
      #pragma unroll
      for (int j = 0; j < 4; ++j) {
        bf16x8 vf = ld_bf16x8(&Vs[(j * 16 + l16) * 64 + ((s * 4 + quad) ^ (l16 & 7)) * 8]);
        O[j] = __builtin_amdgcn_mfma_f32_16x16x32_bf16(pf, vf, O[j], 0, 0, 0);
      }
    }
  }

  // epilogue: O /= l (1/l pulled to O layout), write y [B,T,C] bf16
  const float linv = 1.0f / lrow;
  f32x4 lv;
  #pragma unroll
  for (int r = 0; r < 4; ++r) lv[r] = lane_pull(linv, quad * 4 + r);
  #pragma unroll
  for (int j = 0; j < 4; ++j) {
    O[j] *= lv;
    #pragma unroll
    for (int r = 0; r < 4; ++r) {
      int t  = qt * 64 + w * 16 + quad * 4 + r;
      int ch = h * 64 + j * 16 + l16;
      y[(size_t)(b * TT + t) * CC + ch] = f2bf(O[j][r]);
    }
  }
}

extern "C" void kernel_launch(void* const* d_in, const int* in_sizes, int n_in,
                              void* d_out, int out_size, void* d_ws, size_t ws_size,
                              hipStream_t stream) {
  const float* x  = (const float*)d_in[0];   // [B,T,C]
  const float* Wa = (const float*)d_in[1];   // [C,3C]
  const float* Wp = (const float*)d_in[2];   // [C,C]
  float* out = (float*)d_out;                // [B,T,C] fp32

  u16* ws   = (u16*)d_ws;
  u16* xb   = ws;                             // M*C
  u16* Wab  = xb   + (size_t)MM * CC;         // 3C*C (W_attn^T)
  u16* Wpb  = Wab  + (size_t)3 * CC * CC;     // C*C  (W_proj^T)
  u16* qbuf = Wpb  + (size_t)CC * CC;         // [B,H,T,D]
  u16* kbuf = qbuf + (size_t)MM * CC;         // [B,H,T,D]
  u16* vtb  = kbuf + (size_t)MM * CC;         // [B,H,D,T]
  u16* yb   = vtb  + (size_t)MM * CC;         // [B,T,C]

  k_cast_bf16<<<(MM * CC / 4) / 256, 256, 0, stream>>>(x, xb, MM * CC / 4);
  k_transpose_bf16<<<dim3(3 * CC / 32, CC / 32), 256, 0, stream>>>(Wa, Wab, CC, 3 * CC);
  k_transpose_bf16<<<dim3(CC / 32, CC / 32), 256, 0, stream>>>(Wp, Wpb, CC, CC);
  k_gemm_bt<1><<<dim3(3 * CC / 128, MM / 128), 256, 0, stream>>>(
      xb, Wab, nullptr, qbuf, kbuf, vtb, 3 * CC, CC);
  k_attn<<<64 * 32, 256, 0, stream>>>(qbuf, kbuf, vtb, yb);
  k_gemm_bt<0><<<dim3(CC / 128, MM / 128), 256, 0, stream>>>(
      yb, Wpb, out, nullptr, nullptr, nullptr, CC, CC);
}

// Round 6
// 251.524 us; speedup vs baseline: 1.9728x; 1.0783x over previous
//
#include <hip/hip_runtime.h>
#include <hip/hip_bf16.h>

#define BB 4
#define TT 2048
#define CC 1024
#define HH 16
#define DD 64
#define MM (BB*TT)   // 8192 rows

typedef unsigned short u16;
typedef __bf16 bf16x8 __attribute__((ext_vector_type(8)));
typedef __bf16 bf16x4v __attribute__((ext_vector_type(4)));
typedef u16 u16x8 __attribute__((ext_vector_type(8)));
typedef u16 u16x4 __attribute__((ext_vector_type(4)));
typedef float f32x4 __attribute__((ext_vector_type(4)));

__device__ __forceinline__ u16 f2bf(float f) {
  union { float f; unsigned u; } v; v.f = f;
  unsigned u = v.u;
  return (u16)((u + 0x7fffu + ((u >> 16) & 1u)) >> 16);  // RNE
}
__device__ __forceinline__ float bf2f(u16 s) {
  union { unsigned u; float f; } v; v.u = ((unsigned)s) << 16; return v.f;
}
__device__ __forceinline__ bf16x8 ld_bf16x8(const u16* p) {
  return *reinterpret_cast<const bf16x8*>(p);
}
__device__ __forceinline__ f32x4 zero4() {
  f32x4 z; z[0] = 0.f; z[1] = 0.f; z[2] = 0.f; z[3] = 0.f; return z;
}

// async global->LDS DMA, 16 B/lane. LDS dest = wave-uniform base + lane*16.
__device__ __forceinline__ void gld_lds16(const u16* g, u16* l) {
  __builtin_amdgcn_global_load_lds(
      (const __attribute__((address_space(1))) void*)g,
      (__attribute__((address_space(3))) void*)l, 16, 0, 0);
}
// explicit drain of LDS-DMA: s_waitcnt vmcnt(0)
__device__ __forceinline__ void wait_vm0() { __builtin_amdgcn_s_waitcnt(0x0F70); }

// pull value from lane `srclane` (0..63) of the wave
__device__ __forceinline__ float lane_pull(float x, int srclane) {
  int r = __builtin_amdgcn_ds_bpermute(srclane << 2, __builtin_bit_cast(int, x));
  return __builtin_bit_cast(float, r);
}

// ---------------- cast x (fp32 -> bf16), vectorized ----------------
__global__ void k_cast_bf16(const float* __restrict__ x, u16* __restrict__ o, int n4) {
  int i = blockIdx.x * blockDim.x + threadIdx.x;
  if (i >= n4) return;
  const float4 v = reinterpret_cast<const float4*>(x)[i];
  u16x4 r; r.x = f2bf(v.x); r.y = f2bf(v.y); r.z = f2bf(v.z); r.w = f2bf(v.w);
  reinterpret_cast<u16x4*>(o)[i] = r;
}

// ---------------- transpose-cast W [K][N] fp32 -> Wt [N][K] bf16 ----------------
__global__ void k_transpose_bf16(const float* __restrict__ W, u16* __restrict__ Wt,
                                 int K, int N) {
  __shared__ float tile[32][33];
  int nb = blockIdx.x * 32, kb = blockIdx.y * 32;
  int tx = threadIdx.x & 31, ty = threadIdx.x >> 5;
  #pragma unroll
  for (int i = ty; i < 32; i += 8)
    tile[i][tx] = W[(size_t)(kb + i) * N + nb + tx];
  __syncthreads();
  #pragma unroll
  for (int i = ty; i < 32; i += 8)
    Wt[(size_t)(nb + i) * K + kb + tx] = f2bf(tile[tx][i]);
}

// ---------------- GEMM  C[M,N] = A[M,K](bf16) * Bt[N,K](bf16)^T ----------------
// m97-proven shape: stage(DMA) -> drain -> barrier -> compute -> barrier.
// launch_bounds(256,3): 3 blocks/CU (m97's 874 TF occupancy); VGPR demand ~120.
template<int EPI>
__global__ __launch_bounds__(256, 3)
void k_gemm_bt(const u16* __restrict__ A, const u16* __restrict__ Bt,
               float* __restrict__ outF, u16* __restrict__ qb, u16* __restrict__ kb,
               u16* __restrict__ vt, int N, int K)
{
  __shared__ u16 As[128 * 64];
  __shared__ u16 Bs[128 * 64];
  const int tid  = threadIdx.x;
  const int lane = tid & 63, w = tid >> 6;
  const int l16  = lane & 15, quad = lane >> 4;
  const int wr = w >> 1, wc = w & 1;
  const int m0 = blockIdx.y * 128, n0 = blockIdx.x * 128;
  const int lr8 = lane >> 3, lc8 = lane & 7;

  f32x4 acc[4][4];
  #pragma unroll
  for (int i = 0; i < 4; ++i)
    #pragma unroll
    for (int j = 0; j < 4; ++j) acc[i][j] = zero4();

  for (int k0 = 0; k0 < K; k0 += 64) {
    __syncthreads();
    #pragma unroll
    for (int p = 0; p < 4; ++p) {
      const int row = w * 32 + p * 8 + lr8;
      const int cs  = lc8 ^ (row & 7);
      gld_lds16(A  + (size_t)(m0 + row) * K + k0 + cs * 8, &As[(w * 32 + p * 8) * 64]);
      gld_lds16(Bt + (size_t)(n0 + row) * K + k0 + cs * 8, &Bs[(w * 32 + p * 8) * 64]);
    }
    wait_vm0();
    __syncthreads();
    #pragma unroll
    for (int s = 0; s < 2; ++s) {
      bf16x8 af[4], bfr[4];
      #pragma unroll
      for (int i = 0; i < 4; ++i) {
        int mrow = wr * 64 + i * 16 + l16;
        af[i]  = ld_bf16x8(&As[mrow * 64 + ((s * 4 + quad) ^ (l16 & 7)) * 8]);
        int nrow = wc * 64 + i * 16 + l16;
        bfr[i] = ld_bf16x8(&Bs[nrow * 64 + ((s * 4 + quad) ^ (l16 & 7)) * 8]);
      }
      #pragma unroll
      for (int i = 0; i < 4; ++i)
        #pragma unroll
        for (int j = 0; j < 4; ++j)
          acc[i][j] = __builtin_amdgcn_mfma_f32_16x16x32_bf16(af[i], bfr[j], acc[i][j], 0, 0, 0);
    }
  }

  // epilogue: C/D layout col = lane&15, row = quad*4 + reg (m89-verified)
  #pragma unroll
  for (int i = 0; i < 4; ++i) {
    #pragma unroll
    for (int j = 0; j < 4; ++j) {
      const int n = n0 + wc * 64 + j * 16 + l16;
      const int mb = m0 + wr * 64 + i * 16 + quad * 4;   // 4 consecutive m
      if (EPI == 0) {
        #pragma unroll
        for (int r = 0; r < 4; ++r)
          outF[(size_t)(mb + r) * N + n] = acc[i][j][r];
      } else {
        const int b = mb >> 11, tb = mb & 2047;  // t aligned 4, no b-crossing
        if (n < CC) {
          const int h = n >> 6, d = n & 63;
          #pragma unroll
          for (int r = 0; r < 4; ++r)
            qb[(((size_t)(b * HH + h) * TT + tb + r) << 6) + d] = f2bf(acc[i][j][r]);
        } else if (n < 2 * CC) {
          const int n2 = n - CC; const int h = n2 >> 6, d = n2 & 63;
          #pragma unroll
          for (int r = 0; r < 4; ++r)
            kb[(((size_t)(b * HH + h) * TT + tb + r) << 6) + d] = f2bf(acc[i][j][r]);
        } else {
          // v -> [B,H,D,T]: 4 consecutive t at fixed d -> one 8B packed store
          const int n2 = n - 2 * CC; const int h = n2 >> 6, d = n2 & 63;
          u16x4 cv;
          #pragma unroll
          for (int r = 0; r < 4; ++r) cv[r] = f2bf(acc[i][j][r]);
          *reinterpret_cast<u16x4*>(
              vt + ((size_t)(b * HH + h) * DD + d) * TT + tb) = cv;
        }
      }
    }
  }
}

// ---------------- flash attention v5: S^T layout (r5, unchanged) ----------------
__global__ __launch_bounds__(256, 6)
void k_attn(const u16* __restrict__ qb, const u16* __restrict__ kb,
            const u16* __restrict__ vt, u16* __restrict__ y)
{
  __shared__ u16 Ks[64 * 64];
  __shared__ u16 Vs[64 * 64];
  __shared__ u16 QP[64 * 64];   // Q staging (prologue) then P transform (loop)
  const int tid  = threadIdx.x;
  const int lane = tid & 63, w = tid >> 6;
  const int l16  = lane & 15, quad = lane >> 4;
  const int lr8 = lane >> 3, lc8 = lane & 7;

  const int bx = blockIdx.x;
  const int qt = 31 - (bx >> 6);       // heavy q-tiles first
  const int bh = bx & 63;
  const int h  = bh & 15, b = bh >> 4;

  const u16* qptr = qb + ((size_t)bh * TT + qt * 64) * DD;
  const u16* kptr = kb + (size_t)bh * TT * DD;
  const u16* vptr = vt + (size_t)bh * DD * TT;   // [D][T]

  const float qscale = 0.125f * 1.44269504088896340736f;
  #pragma unroll
  for (int p = 0; p < 2; ++p) {
    const int r = w * 16 + p * 8 + lr8;
    u16x8 v = *reinterpret_cast<const u16x8*>(qptr + (size_t)r * DD + lc8 * 8);
    u16x8 o;
    #pragma unroll
    for (int e = 0; e < 8; ++e) o[e] = f2bf(bf2f(v[e]) * qscale);
    *reinterpret_cast<u16x8*>(&QP[r * 64 + (lc8 ^ lr8) * 8]) = o;
  }
  bf16x8 qf[2];
  #pragma unroll
  for (int s = 0; s < 2; ++s)
    qf[s] = ld_bf16x8(&QP[(w * 16 + l16) * 64 + ((s * 4 + quad) ^ (l16 & 7)) * 8]);

  float mrow = -__builtin_inff(), lrow = 0.f;   // stats for q-row w*16+l16
  f32x4 O[4];
  #pragma unroll
  for (int j = 0; j < 4; ++j) O[j] = zero4();

  const int ktiles = qt + 1;
  for (int kt = 0; kt < ktiles; ++kt) {
    __syncthreads();   // all prior-tile frag reads complete before restaging
    {
      const u16* kt0 = kptr + (size_t)kt * 64 * DD;
      const u16* vt0 = vptr + kt * 64;
      #pragma unroll
      for (int p = 0; p < 2; ++p) {
        const int row = w * 16 + p * 8 + lr8;
        const int cs  = lc8 ^ lr8;
        gld_lds16(kt0 + (size_t)row * DD + cs * 8, &Ks[(w * 16 + p * 8) * 64]);
        gld_lds16(vt0 + (size_t)row * TT + cs * 8, &Vs[(w * 16 + p * 8) * 64]);
      }
    }
    wait_vm0();          // own DMA landed
    __syncthreads();     // everyone's DMA landed

    // S^T[k = j*16+quad*4+r][q = l16] : A = K-frag, B = Q-frag (same layouts)
    f32x4 St[4];
    #pragma unroll
    for (int j = 0; j < 4; ++j) St[j] = zero4();
    #pragma unroll
    for (int s = 0; s < 2; ++s) {
      #pragma unroll
      for (int j = 0; j < 4; ++j) {
        bf16x8 kfr = ld_bf16x8(&Ks[(j * 16 + l16) * 64 + ((s * 4 + quad) ^ (l16 & 7)) * 8]);
        St[j] = __builtin_amdgcn_mfma_f32_16x16x32_bf16(kfr, qf[s], St[j], 0, 0, 0);
      }
    }
    if (kt == qt) {  // diagonal tile: causal mask (local: k > q -> -inf)
      const int qg = w * 16 + l16;
      #pragma unroll
      for (int j = 0; j < 4; ++j)
        #pragma unroll
        for (int r = 0; r < 4; ++r)
          if (j * 16 + quad * 4 + r > qg) St[j][r] = -__builtin_inff();
    }

    // online softmax (exp2 domain); per-lane scalar stats for q = w*16+l16
    float mloc = St[0][0];
    #pragma unroll
    for (int j = 0; j < 4; ++j)
      #pragma unroll
      for (int r = 0; r < 4; ++r) mloc = fmaxf(mloc, St[j][r]);
    mloc = fmaxf(mloc, __shfl_xor(mloc, 16));
    mloc = fmaxf(mloc, __shfl_xor(mloc, 32));
    const float mnew  = fmaxf(mrow, mloc);
    const float alpha = exp2f(mrow - mnew);   // exp2(-inf)=0 on first tile
    float rsum = 0.f;
    #pragma unroll
    for (int j = 0; j < 4; ++j)
      #pragma unroll
      for (int r = 0; r < 4; ++r) {
        float p = exp2f(St[j][r] - mnew);
        St[j][r] = p;
        rsum += p;
      }
    rsum += __shfl_xor(rsum, 16);
    rsum += __shfl_xor(rsum, 32);
    lrow = lrow * alpha + rsum;
    mrow = mnew;

    // alpha -> O layout (row = quad*4+r): pull from lane quad*4+r (l16 == q)
    f32x4 av;
    #pragma unroll
    for (int r = 0; r < 4; ++r) av[r] = lane_pull(alpha, quad * 4 + r);
    #pragma unroll
    for (int j = 0; j < 4; ++j) O[j] *= av;

    // P repack: lane holds k = j*16+quad*4+{0..3} of q-row l16 (k-contiguous)
    #pragma unroll
    for (int j = 0; j < 4; ++j) {
      union { bf16x4v b; u16x4 u; } cv;
      cv.b[0] = (__bf16)St[j][0]; cv.b[1] = (__bf16)St[j][1];
      cv.b[2] = (__bf16)St[j][2]; cv.b[3] = (__bf16)St[j][3];
      const int c = j * 2 + (quad >> 1);               // 16B chunk of k-granule
      const int off = w * 1024 + l16 * 64 + ((c ^ (l16 & 7)) << 3) + ((quad & 1) << 2);
      *reinterpret_cast<u16x4*>(&QP[off]) = cv.u;
    }
    #pragma unroll
    for (int s = 0; s < 2; ++s) {
      bf16x8 pf = ld_bf16x8(&QP[w * 1024 + l16 * 64 + ((s * 4 + quad) ^ (l16 & 7)) * 8]);
      #pragma unroll
      for (int j = 0; j < 4; ++j) {
        bf16x8 vf = ld_bf16x8(&Vs[(j * 16 + l16) * 64 + ((s * 4 + quad) ^ (l16 & 7)) * 8]);
        O[j] = __builtin_amdgcn_mfma_f32_16x16x32_bf16(pf, vf, O[j], 0, 0, 0);
      }
    }
  }

  // epilogue: O /= l (1/l pulled to O layout), write y [B,T,C] bf16
  const float linv = 1.0f / lrow;
  f32x4 lv;
  #pragma unroll
  for (int r = 0; r < 4; ++r) lv[r] = lane_pull(linv, quad * 4 + r);
  #pragma unroll
  for (int j = 0; j < 4; ++j) {
    O[j] *= lv;
    #pragma unroll
    for (int r = 0; r < 4; ++r) {
      int t  = qt * 64 + w * 16 + quad * 4 + r;
      int ch = h * 64 + j * 16 + l16;
      y[(size_t)(b * TT + t) * CC + ch] = f2bf(O[j][r]);
    }
  }
}

extern "C" void kernel_launch(void* const* d_in, const int* in_sizes, int n_in,
                              void* d_out, int out_size, void* d_ws, size_t ws_size,
                              hipStream_t stream) {
  const float* x  = (const float*)d_in[0];   // [B,T,C]
  const float* Wa = (const float*)d_in[1];   // [C,3C]
  const float* Wp = (const float*)d_in[2];   // [C,C]
  float* out = (float*)d_out;                // [B,T,C] fp32

  u16* ws   = (u16*)d_ws;
  u16* xb   = ws;                             // M*C
  u16* Wab  = xb   + (size_t)MM * CC;         // 3C*C (W_attn^T)
  u16* Wpb  = Wab  + (size_t)3 * CC * CC;     // C*C  (W_proj^T)
  u16* qbuf = Wpb  + (size_t)CC * CC;         // [B,H,T,D]
  u16* kbuf = qbuf + (size_t)MM * CC;         // [B,H,T,D]
  u16* vtb  = kbuf + (size_t)MM * CC;         // [B,H,D,T]
  u16* yb   = vtb  + (size_t)MM * CC;         // [B,T,C]

  k_cast_bf16<<<(MM * CC / 4) / 256, 256, 0, stream>>>(x, xb, MM * CC / 4);
  k_transpose_bf16<<<dim3(3 * CC / 32, CC / 32), 256, 0, stream>>>(Wa, Wab, CC, 3 * CC);
  k_transpose_bf16<<<dim3(CC / 32, CC / 32), 256, 0, stream>>>(Wp, Wpb, CC, CC);
  k_gemm_bt<1><<<dim3(3 * CC / 128, MM / 128), 256, 0, stream>>>(
      xb, Wab, nullptr, qbuf, kbuf, vtb, 3 * CC, CC);
  k_attn<<<64 * 32, 256, 0, stream>>>(qbuf, kbuf, vtb, yb);
  k_gemm_bt<0><<<dim3(CC / 128, MM / 128), 256, 0, stream>>>(
      yb, Wpb, out, nullptr, nullptr, nullptr, CC, CC);
}